// Round 7
// baseline (115.643 us; speedup 1.0000x reference)
//
#include <hip/hip_runtime.h>
#include <hip/hip_bf16.h>

// B=64, M=16, T=2048, L=64, K=32, N=1985
#define B_ 64
#define M_ 16
#define T_ 2048
#define L_ 64
#define K_ 32
#define N_ (T_ - L_ + 1)   // 1985
#define KMN (K_ * M_ * N_) // 1,016,320 (= 4 * 254,080 exactly)
#define TN 64              // n-positions per block
#define NTH 512            // 8 waves: wave = (wg, wsub); wg = m-group (m 8wg..8wg+7),
                           // wsub = n-subtile [16*wsub, +16). m-split HALVES each
                           // wave's serial m-chain and DOUBLES waves/block at the
                           // same LDS -> wave-cap residency 4 blocks/CU (32 waves).
#define XROW 144           // per-plane row elems; need j<=123. 144 elems = 72 dw
                           // == 8 (mod 32) -> planes at bank offsets {0,8,16,24}:
                           // uniform 4 touches/bank = the 512B/wave floor.
#define STSTR 72           // st row stride elems (16B-aligned b128 reads)
#define SQSTR 64           // sqw row stride

typedef __attribute__((ext_vector_type(8))) short bf16x8;
typedef __attribute__((ext_vector_type(4))) float f32x4;

__device__ __forceinline__ unsigned short f2bf(float f) {
    __hip_bfloat16 h = __float2bfloat16(f);
    return __builtin_bit_cast(unsigned short, h);
}

// pen[i] = elu(-pmap[i]) + 2 (flat over K*M*N); ss[k] = sum shp^2; out[] = +inf.
__global__ void pen_init_kernel(const float* __restrict__ pmap,
                                const float* __restrict__ shp,
                                float* __restrict__ pen,
                                float* __restrict__ ss_ws,
                                unsigned* __restrict__ out) {
    const int gid = blockIdx.x * 256 + threadIdx.x;
    if (gid < B_ * K_) out[gid] = 0x7F800000u;  // +inf
    if (gid < K_) {
        float s = 0.f;
        for (int l = 0; l < L_; ++l) { float v = shp[gid * L_ + l]; s = fmaf(v, v, s); }
        ss_ws[gid] = s;
    }
#pragma unroll
    for (int half = 0; half < 2; ++half) {
        const int item = gid + half * (KMN / 8);     // KMN/4 = 254080 = 2*127040
        if (item < KMN / 4) {
            const int i4 = item * 4;
            float4 p = *(const float4*)(pmap + i4);
            float4 r;
            r.x = (p.x < 0.f) ? (2.f - p.x) : (__expf(-p.x) + 1.f);
            r.y = (p.y < 0.f) ? (2.f - p.y) : (__expf(-p.y) + 1.f);
            r.z = (p.z < 0.f) ? (2.f - p.z) : (__expf(-p.z) + 1.f);
            r.w = (p.w < 0.f) ? (2.f - p.w) : (__expf(-p.w) + 1.f);
            *(float4*)(pen + i4) = r;
        }
    }
}

// LDS: 18432 (xbuf4) + 4608 (st) + 4096 (sqw) = 27136 B. Residency: LDS allows 6
// blocks/CU; the 32-wave/CU cap allows 4 (= 100% wave occupancy).
// __launch_bounds__(512, 8): VGPR cap 64 (r0 body measured 40; m-loop halved).
__global__ __launch_bounds__(NTH, 8)
void shapelet_mfma_kernel(const float* __restrict__ x,
                          const float* __restrict__ shp,
                          const float* __restrict__ pen,
                          const float* __restrict__ ss_ws,
                          unsigned* __restrict__ out) {
    __shared__ __align__(16) unsigned short xbuf4[M_][4][XROW];
    __shared__ __align__(16) unsigned short st[K_][STSTR];   // shapelets bf16
    __shared__ __align__(16) float sqw[M_][SQSTR];           // fp32 sliding sum x^2

    const int tid = threadIdx.x;
    const int n0 = blockIdx.x * TN;
    const int b  = blockIdx.y;
    const bool fast = (n0 + 128 <= T_);   // false only for last tile (n0=1984)

    // ---- stage shapelets st[k][l] bf16: 512 items, one per thread ----
    {
        const int k = tid >> 4, l4 = (tid & 15) * 4;
        float4 v = *(const float4*)(shp + k * L_ + l4);
        ushort4 sv = { f2bf(v.x), f2bf(v.y), f2bf(v.z), f2bf(v.w) };
        *(ushort4*)&st[k][l4] = sv;
    }

    // ---- stage x as 4 shifted bf16 planes: 496 items over 512 threads ----
    const float* xb = x + ((size_t)b * M_) * T_ + n0;
    if (tid < M_ * 31) {
        const int m = tid / 31, j4 = (tid - m * 31) * 4;     // j4 in {0,4,...,120}
        const float* src = xb + m * T_ + j4;
        float h[8];
        if (fast) {
            float4 v0 = *(const float4*)src;
            float4 v1 = *(const float4*)(src + 4);
            h[0] = v0.x; h[1] = v0.y; h[2] = v0.z; h[3] = v0.w;
            h[4] = v1.x; h[5] = v1.y; h[6] = v1.z; h[7] = v1.w;
        } else {
#pragma unroll
            for (int i = 0; i < 8; ++i)
                h[i] = (n0 + j4 + i < T_) ? src[i] : 0.f;
        }
        unsigned short hb[8];
#pragma unroll
        for (int i = 0; i < 8; ++i) hb[i] = f2bf(h[i]);
#pragma unroll
        for (int s = 0; s < 4; ++s) {
            ushort4 sv = { hb[s], hb[s + 1], hb[s + 2], hb[s + 3] };
            *(ushort4*)&xbuf4[m][s][j4] = sv;
        }
    }
    // ---- sqw fp32 sliding window: 8 threads per m, 8 n each (threads 0..127) ----
    if (tid < M_ * 8) {
        const int m = tid >> 3, j0 = (tid & 7) * 8;
        const float* xr = x + ((size_t)b * M_ + m) * T_ + n0;
        float s = 0.f;
        if (fast) {
#pragma unroll
            for (int qd = 0; qd < 16; ++qd) {
                float4 v = *(const float4*)(xr + j0 + qd * 4);
                s = fmaf(v.x, v.x, s); s = fmaf(v.y, v.y, s);
                s = fmaf(v.z, v.z, s); s = fmaf(v.w, v.w, s);
            }
            sqw[m][j0] = s;
#pragma unroll
            for (int d = 1; d < 8; ++d) {
                float a = xr[j0 + d + L_ - 1], r = xr[j0 + d - 1];
                s += a * a - r * r;
                sqw[m][j0 + d] = s;
            }
        } else {
            for (int l = 0; l < L_; ++l) {
                float v = (n0 + j0 + l < T_) ? xr[j0 + l] : 0.f;
                s = fmaf(v, v, s);
            }
            sqw[m][j0] = s;
            for (int d = 1; d < 8; ++d) {
                float a = (n0 + j0 + d + L_ - 1 < T_) ? xr[j0 + d + L_ - 1] : 0.f;
                float r = (n0 + j0 + d - 1 < T_) ? xr[j0 + d - 1] : 0.f;
                s += a * a - r * r;
                sqw[m][j0 + d] = s;
            }
        }
    }

    // ---- per-lane MFMA coordinates ----
    const int lane = tid & 63;
    const int wsub = (tid >> 6) & 3;   // n-subtile [16*wsub, 16*wsub+16)
    const int wg   = tid >> 8;         // m-group: m in [8*wg, 8*wg+8)
    const int rl = lane & 15;          // A-row (n within subtile) / B-col (k)
    const int q  = lane >> 4;          // quad
    const int sp = rl & 3;                            // shift plane
    const int e0 = 16 * wsub + 8 * q + (rl & ~3);     // 4-aligned elem base (max 84)
    const int eq = e0 >> 2;                           // uint2 index (max 21; +9 fits)
    const int nrow = n0 + 16 * wsub + 4 * q;          // lane's 4 output rows: nrow + r

    const float ssk0 = ss_ws[rl], ssk1 = ss_ws[16 + rl];
    __syncthreads();

    // b_frags (registers, whole kernel): st[16t+rl][8q+32h .. +7] — same for both wg
    bf16x8 bfr[2][2];
#pragma unroll
    for (int t = 0; t < 2; ++t)
#pragma unroll
        for (int h = 0; h < 2; ++h)
            bfr[t][h] = *(const bf16x8*)&st[16 * t + rl][8 * q + 32 * h];

    const float* pr0 = pen + (size_t)rl * (M_ * N_) + nrow + (size_t)(8 * wg) * N_;
    const float* pr1 = pr0 + (size_t)16 * M_ * N_;     // k = rl + 16

    f32x4 wd0 = (f32x4)0.f, wd1 = (f32x4)0.f;
    const f32x4 zero = (f32x4)0.f;

    // ---- m-loop over THIS GROUP's 8 m's (r0 body verbatim, chain halved) ----
#pragma unroll 2
    for (int mm = 0; mm < M_ / 2; ++mm) {
        const int m = 8 * wg + mm;
        float4 p0, p1;
        if (fast) {
            p0 = *(const float4*)(pr0 + (size_t)mm * N_);
            p1 = *(const float4*)(pr1 + (size_t)mm * N_);
        } else {
            p0 = make_float4(2.f, 2.f, 2.f, 2.f);   // masked at the min
            p1 = make_float4(2.f, 2.f, 2.f, 2.f);
            const float* r0_ = pr0 + (size_t)mm * N_;
            const float* r1_ = pr1 + (size_t)mm * N_;
            if (nrow     < N_) { p0.x = r0_[0]; p1.x = r1_[0]; }
            if (nrow + 1 < N_) { p0.y = r0_[1]; p1.y = r1_[1]; }
            if (nrow + 2 < N_) { p0.z = r0_[2]; p1.z = r1_[2]; }
            if (nrow + 3 < N_) { p0.w = r0_[3]; p1.w = r1_[3]; }
        }

        const uint2* prow = (const uint2*)&xbuf4[m][sp][0];
        uint2 lo0 = prow[eq],     hi0 = prow[eq + 1];
        uint2 lo1 = prow[eq + 8], hi1 = prow[eq + 9];
        union { uint2 u2[2]; bf16x8 v; } fa0, fa1;
        fa0.u2[0] = lo0; fa0.u2[1] = hi0;
        fa1.u2[0] = lo1; fa1.u2[1] = hi1;

        f32x4 c0_ = __builtin_amdgcn_mfma_f32_16x16x32_bf16(fa0.v, bfr[0][0], zero, 0, 0, 0);
        c0_       = __builtin_amdgcn_mfma_f32_16x16x32_bf16(fa1.v, bfr[0][1], c0_, 0, 0, 0);
        f32x4 c1_ = __builtin_amdgcn_mfma_f32_16x16x32_bf16(fa0.v, bfr[1][0], zero, 0, 0, 0);
        c1_       = __builtin_amdgcn_mfma_f32_16x16x32_bf16(fa1.v, bfr[1][1], c1_, 0, 0, 0);

        f32x4 sq = *(const f32x4*)&sqw[m][16 * wsub + 4 * q];
        const float pe0[4] = { p0.x, p0.y, p0.z, p0.w };
        const float pe1[4] = { p1.x, p1.y, p1.z, p1.w };
#pragma unroll
        for (int r = 0; r < 4; ++r) {
            float t0v = fmaf(-2.f, c0_[r], sq[r] + ssk0);
            wd0[r] = fmaf(pe0[r], t0v, wd0[r]);
            float t1v = fmaf(-2.f, c1_[r], sq[r] + ssk1);
            wd1[r] = fmaf(pe1[r], t1v, wd1[r]);
        }
    }

    // ---- combine the two m-groups: B writes partials into dead xbuf space ----
    __syncthreads();                              // all m-loops done, xbuf dead
    float* scr = (float*)&xbuf4[0][0][0];         // [4 wsub][64 lane][8] = 8 KB
    if (wg == 1) {
        float* dst = scr + ((wsub * 64 + lane) * 8);
#pragma unroll
        for (int r = 0; r < 4; ++r) { dst[r] = wd0[r]; dst[4 + r] = wd1[r]; }
    }
    __syncthreads();

    if (wg == 0) {
        const float* src = scr + ((wsub * 64 + lane) * 8);
#pragma unroll
        for (int r = 0; r < 4; ++r) { wd0[r] += src[r]; wd1[r] += src[4 + r]; }

        // ---- min: 4 rows -> quads (shfl) -> cross-wave LDS -> atomic ----
        float* red = (float*)&sqw[0][0];          // [4 wsub][32]
#pragma unroll
        for (int t = 0; t < 2; ++t) {
            float lmin = __int_as_float(0x7F800000);
            const f32x4 wdv = t ? wd1 : wd0;
#pragma unroll
            for (int r = 0; r < 4; ++r)
                if (nrow + r < N_) lmin = fminf(lmin, wdv[r]);
            lmin = fminf(lmin, __shfl_xor(lmin, 16));
            lmin = fminf(lmin, __shfl_xor(lmin, 32));
            if (q == 0) red[wsub * 32 + t * 16 + rl] = lmin;
        }
    }
    __syncthreads();
    if (tid < K_) {
        const float* red = (const float*)&sqw[0][0];
        float v = fminf(fminf(red[tid], red[32 + tid]),
                        fminf(red[64 + tid], red[96 + tid]));
        atomicMin(out + (size_t)b * K_ + tid, __float_as_uint(fmaxf(v, 0.f)));
    }
}

extern "C" void kernel_launch(void* const* d_in, const int* in_sizes, int n_in,
                              void* d_out, int out_size, void* d_ws, size_t ws_size,
                              hipStream_t stream) {
    const float* x    = (const float*)d_in[0];   // (B, M, T)
    const float* shp  = (const float*)d_in[1];   // (K, L)
    const float* pmap = (const float*)d_in[2];   // (K, M, N)
    unsigned* out = (unsigned*)d_out;            // (B, K) float bits
    float* pen   = (float*)d_ws;                 // (K, M, N) elu(-pmap)+2, 3.9 MB
    float* ss_ws = pen + KMN;                    // (K,) fp32 sum s^2

    pen_init_kernel<<<dim3((KMN / 8 + 255) / 256), dim3(256), 0, stream>>>(
        pmap, shp, pen, ss_ws, out);

    dim3 grid((N_ + TN - 1) / TN, B_);           // 32 x 64 = 2048 blocks of 512
    shapelet_mfma_kernel<<<grid, dim3(NTH), 0, stream>>>(x, shp, pen, ss_ws, out);
}

// Round 8
// 104.127 us; speedup vs baseline: 1.1106x; 1.1106x over previous
//
#include <hip/hip_runtime.h>
#include <hip/hip_bf16.h>

// B=64, M=16, T=2048, L=64, K=32, N=1985
#define B_ 64
#define M_ 16
#define T_ 2048
#define L_ 64
#define K_ 32
#define N_ (T_ - L_ + 1)   // 1985
#define KMN (K_ * M_ * N_) // 1,016,320 (= 4 * 254,080 exactly)
#define TN 64              // n-positions per block
#define NTH 512            // 8 waves: wave = (wg, wsub); wg = m-group (m 8wg..8wg+7),
                           // wsub = n-subtile [16*wsub, +16). m-split HALVES each
                           // wave's serial m-chain and DOUBLES waves/block at the
                           // same LDS. r7 PROVED occupancy 56% with this shape;
                           // it also proved __launch_bounds__(512,8)'s 32-VGPR cap
                           // spills ~33 MB of scratch (WRITE 28 MB). This round:
                           // (512,4) -> cap 128, compiler uses ~56-72, no spill;
                           // hardware can still resident 4 blocks/CU if VGPR<=64.
#define XROW 144           // per-plane row elems; need j<=123. 144 elems = 72 dw
                           // == 8 (mod 32) -> planes at bank offsets {0,8,16,24}:
                           // uniform 4 touches/bank = the 512B/wave floor.
#define STSTR 72           // st row stride elems (16B-aligned b128 reads)
#define SQSTR 64           // sqw row stride

typedef __attribute__((ext_vector_type(8))) short bf16x8;
typedef __attribute__((ext_vector_type(4))) float f32x4;

__device__ __forceinline__ unsigned short f2bf(float f) {
    __hip_bfloat16 h = __float2bfloat16(f);
    return __builtin_bit_cast(unsigned short, h);
}

// pen[i] = elu(-pmap[i]) + 2 (flat over K*M*N); ss[k] = sum shp^2; out[] = +inf.
__global__ void pen_init_kernel(const float* __restrict__ pmap,
                                const float* __restrict__ shp,
                                float* __restrict__ pen,
                                float* __restrict__ ss_ws,
                                unsigned* __restrict__ out) {
    const int gid = blockIdx.x * 256 + threadIdx.x;
    if (gid < B_ * K_) out[gid] = 0x7F800000u;  // +inf
    if (gid < K_) {
        float s = 0.f;
        for (int l = 0; l < L_; ++l) { float v = shp[gid * L_ + l]; s = fmaf(v, v, s); }
        ss_ws[gid] = s;
    }
#pragma unroll
    for (int half = 0; half < 2; ++half) {
        const int item = gid + half * (KMN / 8);     // KMN/4 = 254080 = 2*127040
        if (item < KMN / 4) {
            const int i4 = item * 4;
            float4 p = *(const float4*)(pmap + i4);
            float4 r;
            r.x = (p.x < 0.f) ? (2.f - p.x) : (__expf(-p.x) + 1.f);
            r.y = (p.y < 0.f) ? (2.f - p.y) : (__expf(-p.y) + 1.f);
            r.z = (p.z < 0.f) ? (2.f - p.z) : (__expf(-p.z) + 1.f);
            r.w = (p.w < 0.f) ? (2.f - p.w) : (__expf(-p.w) + 1.f);
            *(float4*)(pen + i4) = r;
        }
    }
}

// LDS: 18432 (xbuf4) + 4608 (st) + 4096 (sqw) = 27136 B.
// __launch_bounds__(512, 4): VGPR cap 128 — the r7 structure minus the spill.
__global__ __launch_bounds__(NTH, 4)
void shapelet_mfma_kernel(const float* __restrict__ x,
                          const float* __restrict__ shp,
                          const float* __restrict__ pen,
                          const float* __restrict__ ss_ws,
                          unsigned* __restrict__ out) {
    __shared__ __align__(16) unsigned short xbuf4[M_][4][XROW];
    __shared__ __align__(16) unsigned short st[K_][STSTR];   // shapelets bf16
    __shared__ __align__(16) float sqw[M_][SQSTR];           // fp32 sliding sum x^2

    const int tid = threadIdx.x;
    const int n0 = blockIdx.x * TN;
    const int b  = blockIdx.y;
    const bool fast = (n0 + 128 <= T_);   // false only for last tile (n0=1984)

    // ---- stage shapelets st[k][l] bf16: 512 items, one per thread ----
    {
        const int k = tid >> 4, l4 = (tid & 15) * 4;
        float4 v = *(const float4*)(shp + k * L_ + l4);
        ushort4 sv = { f2bf(v.x), f2bf(v.y), f2bf(v.z), f2bf(v.w) };
        *(ushort4*)&st[k][l4] = sv;
    }

    // ---- stage x as 4 shifted bf16 planes: 496 items over 512 threads ----
    const float* xb = x + ((size_t)b * M_) * T_ + n0;
    if (tid < M_ * 31) {
        const int m = tid / 31, j4 = (tid - m * 31) * 4;     // j4 in {0,4,...,120}
        const float* src = xb + m * T_ + j4;
        float h[8];
        if (fast) {
            float4 v0 = *(const float4*)src;
            float4 v1 = *(const float4*)(src + 4);
            h[0] = v0.x; h[1] = v0.y; h[2] = v0.z; h[3] = v0.w;
            h[4] = v1.x; h[5] = v1.y; h[6] = v1.z; h[7] = v1.w;
        } else {
#pragma unroll
            for (int i = 0; i < 8; ++i)
                h[i] = (n0 + j4 + i < T_) ? src[i] : 0.f;
        }
        unsigned short hb[8];
#pragma unroll
        for (int i = 0; i < 8; ++i) hb[i] = f2bf(h[i]);
#pragma unroll
        for (int s = 0; s < 4; ++s) {
            ushort4 sv = { hb[s], hb[s + 1], hb[s + 2], hb[s + 3] };
            *(ushort4*)&xbuf4[m][s][j4] = sv;
        }
    }
    // ---- sqw fp32 sliding window: 8 threads per m, 8 n each (threads 0..127) ----
    if (tid < M_ * 8) {
        const int m = tid >> 3, j0 = (tid & 7) * 8;
        const float* xr = x + ((size_t)b * M_ + m) * T_ + n0;
        float s = 0.f;
        if (fast) {
#pragma unroll
            for (int qd = 0; qd < 16; ++qd) {
                float4 v = *(const float4*)(xr + j0 + qd * 4);
                s = fmaf(v.x, v.x, s); s = fmaf(v.y, v.y, s);
                s = fmaf(v.z, v.z, s); s = fmaf(v.w, v.w, s);
            }
            sqw[m][j0] = s;
#pragma unroll
            for (int d = 1; d < 8; ++d) {
                float a = xr[j0 + d + L_ - 1], r = xr[j0 + d - 1];
                s += a * a - r * r;
                sqw[m][j0 + d] = s;
            }
        } else {
            for (int l = 0; l < L_; ++l) {
                float v = (n0 + j0 + l < T_) ? xr[j0 + l] : 0.f;
                s = fmaf(v, v, s);
            }
            sqw[m][j0] = s;
            for (int d = 1; d < 8; ++d) {
                float a = (n0 + j0 + d + L_ - 1 < T_) ? xr[j0 + d + L_ - 1] : 0.f;
                float r = (n0 + j0 + d - 1 < T_) ? xr[j0 + d - 1] : 0.f;
                s += a * a - r * r;
                sqw[m][j0 + d] = s;
            }
        }
    }

    // ---- per-lane MFMA coordinates ----
    const int lane = tid & 63;
    const int wsub = (tid >> 6) & 3;   // n-subtile [16*wsub, 16*wsub+16)
    const int wg   = tid >> 8;         // m-group: m in [8*wg, 8*wg+8)
    const int rl = lane & 15;          // A-row (n within subtile) / B-col (k)
    const int q  = lane >> 4;          // quad
    const int sp = rl & 3;                            // shift plane
    const int e0 = 16 * wsub + 8 * q + (rl & ~3);     // 4-aligned elem base (max 84)
    const int eq = e0 >> 2;                           // uint2 index (max 21; +9 fits)
    const int nrow = n0 + 16 * wsub + 4 * q;          // lane's 4 output rows: nrow + r

    const float ssk0 = ss_ws[rl], ssk1 = ss_ws[16 + rl];
    __syncthreads();

    // b_frags (registers, whole kernel): st[16t+rl][8q+32h .. +7] — same for both wg
    bf16x8 bfr[2][2];
#pragma unroll
    for (int t = 0; t < 2; ++t)
#pragma unroll
        for (int h = 0; h < 2; ++h)
            bfr[t][h] = *(const bf16x8*)&st[16 * t + rl][8 * q + 32 * h];

    const float* pr0 = pen + (size_t)rl * (M_ * N_) + nrow + (size_t)(8 * wg) * N_;
    const float* pr1 = pr0 + (size_t)16 * M_ * N_;     // k = rl + 16

    f32x4 wd0 = (f32x4)0.f, wd1 = (f32x4)0.f;
    const f32x4 zero = (f32x4)0.f;

    // ---- m-loop over THIS GROUP's 8 m's (r0 body verbatim, chain halved) ----
#pragma unroll 2
    for (int mm = 0; mm < M_ / 2; ++mm) {
        const int m = 8 * wg + mm;
        float4 p0, p1;
        if (fast) {
            p0 = *(const float4*)(pr0 + (size_t)mm * N_);
            p1 = *(const float4*)(pr1 + (size_t)mm * N_);
        } else {
            p0 = make_float4(2.f, 2.f, 2.f, 2.f);   // masked at the min
            p1 = make_float4(2.f, 2.f, 2.f, 2.f);
            const float* r0_ = pr0 + (size_t)mm * N_;
            const float* r1_ = pr1 + (size_t)mm * N_;
            if (nrow     < N_) { p0.x = r0_[0]; p1.x = r1_[0]; }
            if (nrow + 1 < N_) { p0.y = r0_[1]; p1.y = r1_[1]; }
            if (nrow + 2 < N_) { p0.z = r0_[2]; p1.z = r1_[2]; }
            if (nrow + 3 < N_) { p0.w = r0_[3]; p1.w = r1_[3]; }
        }

        const uint2* prow = (const uint2*)&xbuf4[m][sp][0];
        uint2 lo0 = prow[eq],     hi0 = prow[eq + 1];
        uint2 lo1 = prow[eq + 8], hi1 = prow[eq + 9];
        union { uint2 u2[2]; bf16x8 v; } fa0, fa1;
        fa0.u2[0] = lo0; fa0.u2[1] = hi0;
        fa1.u2[0] = lo1; fa1.u2[1] = hi1;

        f32x4 c0_ = __builtin_amdgcn_mfma_f32_16x16x32_bf16(fa0.v, bfr[0][0], zero, 0, 0, 0);
        c0_       = __builtin_amdgcn_mfma_f32_16x16x32_bf16(fa1.v, bfr[0][1], c0_, 0, 0, 0);
        f32x4 c1_ = __builtin_amdgcn_mfma_f32_16x16x32_bf16(fa0.v, bfr[1][0], zero, 0, 0, 0);
        c1_       = __builtin_amdgcn_mfma_f32_16x16x32_bf16(fa1.v, bfr[1][1], c1_, 0, 0, 0);

        f32x4 sq = *(const f32x4*)&sqw[m][16 * wsub + 4 * q];
        const float pe0[4] = { p0.x, p0.y, p0.z, p0.w };
        const float pe1[4] = { p1.x, p1.y, p1.z, p1.w };
#pragma unroll
        for (int r = 0; r < 4; ++r) {
            float t0v = fmaf(-2.f, c0_[r], sq[r] + ssk0);
            wd0[r] = fmaf(pe0[r], t0v, wd0[r]);
            float t1v = fmaf(-2.f, c1_[r], sq[r] + ssk1);
            wd1[r] = fmaf(pe1[r], t1v, wd1[r]);
        }
    }

    // ---- combine the two m-groups: B writes partials into dead xbuf space ----
    __syncthreads();                              // all m-loops done, xbuf dead
    float* scr = (float*)&xbuf4[0][0][0];         // [4 wsub][64 lane][8] = 8 KB
    if (wg == 1) {
        float* dst = scr + ((wsub * 64 + lane) * 8);
#pragma unroll
        for (int r = 0; r < 4; ++r) { dst[r] = wd0[r]; dst[4 + r] = wd1[r]; }
    }
    __syncthreads();

    if (wg == 0) {
        const float* src = scr + ((wsub * 64 + lane) * 8);
#pragma unroll
        for (int r = 0; r < 4; ++r) { wd0[r] += src[r]; wd1[r] += src[4 + r]; }

        // ---- min: 4 rows -> quads (shfl) -> cross-wave LDS -> atomic ----
        float* red = (float*)&sqw[0][0];          // [4 wsub][32]
#pragma unroll
        for (int t = 0; t < 2; ++t) {
            float lmin = __int_as_float(0x7F800000);
            const f32x4 wdv = t ? wd1 : wd0;
#pragma unroll
            for (int r = 0; r < 4; ++r)
                if (nrow + r < N_) lmin = fminf(lmin, wdv[r]);
            lmin = fminf(lmin, __shfl_xor(lmin, 16));
            lmin = fminf(lmin, __shfl_xor(lmin, 32));
            if (q == 0) red[wsub * 32 + t * 16 + rl] = lmin;
        }
    }
    __syncthreads();
    if (tid < K_) {
        const float* red = (const float*)&sqw[0][0];
        float v = fminf(fminf(red[tid], red[32 + tid]),
                        fminf(red[64 + tid], red[96 + tid]));
        atomicMin(out + (size_t)b * K_ + tid, __float_as_uint(fmaxf(v, 0.f)));
    }
}

extern "C" void kernel_launch(void* const* d_in, const int* in_sizes, int n_in,
                              void* d_out, int out_size, void* d_ws, size_t ws_size,
                              hipStream_t stream) {
    const float* x    = (const float*)d_in[0];   // (B, M, T)
    const float* shp  = (const float*)d_in[1];   // (K, L)
    const float* pmap = (const float*)d_in[2];   // (K, M, N)
    unsigned* out = (unsigned*)d_out;            // (B, K) float bits
    float* pen   = (float*)d_ws;                 // (K, M, N) elu(-pmap)+2, 3.9 MB
    float* ss_ws = pen + KMN;                    // (K,) fp32 sum s^2

    pen_init_kernel<<<dim3((KMN / 8 + 255) / 256), dim3(256), 0, stream>>>(
        pmap, shp, pen, ss_ws, out);

    dim3 grid((N_ + TN - 1) / TN, B_);           // 32 x 64 = 2048 blocks of 512
    shapelet_mfma_kernel<<<grid, dim3(NTH), 0, stream>>>(x, shp, pen, ss_ws, out);
}